// Round 9
// baseline (1122.216 us; speedup 1.0000x reference)
//
#include <hip/hip_runtime.h>
#include <math.h>

#define N_NODES 65536
#define F_IN 128
#define D_MODEL 256
#define E_EDGES 524288
#define EE_EDGES 589824   /* E + N self loops */
#define SEQ_LEN 2049
#define SEQ_PAD 2112      /* 33*64 */
#define NHEAD 8
#define HDIM 32
#define NCLS 10
#define NSPLIT 4          /* attention KV splits */

typedef unsigned short u16;
typedef __attribute__((ext_vector_type(8))) short s8v;   // 8 x bf16 (4 VGPR)
typedef __attribute__((ext_vector_type(4))) float f4v;   // 4 x f32 acc

__device__ __forceinline__ u16 f2bf(float f)
{
    union { float f; unsigned u; } v; v.f = f;
    unsigned r = v.u + 0x7FFF + ((v.u >> 16) & 1);
    return (u16)(r >> 16);
}
__device__ __forceinline__ float bf2f(u16 h)
{
    union { unsigned u; float f; } v; v.u = ((unsigned)h) << 16;
    return v.f;
}

// ---------------------------------------------------------------------------
// prep: W [K,N] fp32 -> Oh (optionally Ol) [N,K] bf16; optional per-K scale
// (scale = LN gamma folded into the weight: W'[k][n] = s[k]*W[k][n])
// ---------------------------------------------------------------------------
__global__ __launch_bounds__(256) void prep_weight(
    const float* __restrict__ W, u16* __restrict__ Oh, u16* __restrict__ Ol,
    int K, int N, long long strideW, long long strideO, int write_lo,
    const float* __restrict__ scale)
{
    const float* Wz = W + (size_t)blockIdx.z * strideW;
    u16* Ohz = Oh + (size_t)blockIdx.z * strideO;
    u16* Olz = Ol + (size_t)blockIdx.z * strideO;
    const float* scz = scale ? scale + (size_t)blockIdx.z * D_MODEL : nullptr;
    __shared__ u16 th[64][68];
    __shared__ u16 tl[64][68];
    int kb = blockIdx.x * 64, nb = blockIdx.y * 64;
    int t = threadIdx.x;
    int kr = t >> 4, nc = (t & 15) * 4;
#pragma unroll
    for (int i = 0; i < 4; ++i) {
        int k = kr + i * 16;
        float sv = scz ? scz[kb + k] : 1.f;
        float4 v = *(const float4*)(Wz + (size_t)(kb + k) * N + nb + nc);
        float vv[4] = {v.x * sv, v.y * sv, v.z * sv, v.w * sv};
#pragma unroll
        for (int e = 0; e < 4; ++e) {
            u16 h = f2bf(vv[e]);
            th[k][nc + e] = h;
            if (write_lo) tl[k][nc + e] = f2bf(vv[e] - bf2f(h));
        }
    }
    __syncthreads();
    int nr = t >> 4, kc = (t & 15) * 4;
#pragma unroll
    for (int i = 0; i < 4; ++i) {
        int n = nr + i * 16;
        uint2 oh;
        oh.x = (unsigned)th[kc + 0][n] | ((unsigned)th[kc + 1][n] << 16);
        oh.y = (unsigned)th[kc + 2][n] | ((unsigned)th[kc + 3][n] << 16);
        *(uint2*)(Ohz + (size_t)(nb + n) * K + kb + kc) = oh;
        if (write_lo) {
            uint2 ol;
            ol.x = (unsigned)tl[kc + 0][n] | ((unsigned)tl[kc + 1][n] << 16);
            ol.y = (unsigned)tl[kc + 2][n] | ((unsigned)tl[kc + 3][n] << 16);
            *(uint2*)(Olz + (size_t)(nb + n) * K + kb + kc) = ol;
        }
    }
}

// out[z][n] = sum_k lnb[z][k] * W[z][k][n] + b0[z][n]   (LN beta fold)
__global__ void bias_fold(const float* __restrict__ lnb, const float* __restrict__ W,
                          const float* __restrict__ b0, float* __restrict__ out,
                          int N, long long strideW)
{
    int z = blockIdx.y;
    int n = blockIdx.x * 256 + threadIdx.x;
    if (n >= N) return;
    const float* Wz = W + (size_t)z * strideW;
    const float* lz = lnb + (size_t)z * D_MODEL;
    float acc = b0[(size_t)z * N + n];
    for (int k = 0; k < D_MODEL; ++k) acc += lz[k] * Wz[(size_t)k * N + n];
    out[(size_t)z * N + n] = acc;
}

// per-row LN stats: mu, rstd. 4 rows/block (1 wave each).
__global__ __launch_bounds__(256) void ln_stats(
    const float* __restrict__ seq, float* __restrict__ mu, float* __restrict__ rs)
{
    int row = blockIdx.x * 4 + (threadIdx.x >> 6);
    int lane = threadIdx.x & 63;
    if (row >= SEQ_LEN) return;
    float4 v = *(const float4*)(seq + (size_t)row * 256 + (lane << 2));
    float s1 = v.x + v.y + v.z + v.w;
    float s2 = v.x * v.x + v.y * v.y + v.z * v.z + v.w * v.w;
#pragma unroll
    for (int off = 32; off; off >>= 1) {
        s1 += __shfl_xor(s1, off);
        s2 += __shfl_xor(s2, off);
    }
    if (lane == 0) {
        float m = s1 * (1.f / 256.f);
        float var = s2 * (1.f / 256.f) - m * m;
        mu[row] = m;
        rs[row] = rsqrtf(var + 1e-5f);
    }
}

// ---------------------------------------------------------------------------
// bf16 MFMA GEMM. TERMS=3: hi/lo 3-term; TERMS=1: plain bf16.
// APRE=1: A bf16 pre-split. FATT=1: A = attention partials (Opart fp32,
//   combined on the fly with Mp/Lp; ATOM=1, Kc=64). LNS=1: A fp32,
//   standardized (x-Mp[row])*Lp[row] during staging (precomputed stats).
// OB=1: bf16 C. ATOM=1: fp32 atomicAdd; bias added by blockIdx.z==0.
// ---------------------------------------------------------------------------
template<int ACT, int RES, int ATOM, int OB, int APRE, int TERMS, int FATT, int LNS>
__global__ __launch_bounds__(256) void hgemm(
    const void* __restrict__ A, const u16* __restrict__ Al2,
    const u16* __restrict__ Bh, const u16* __restrict__ Bl,
    const float* __restrict__ bias, const float* __restrict__ Rsd,
    float* __restrict__ C, const float* __restrict__ Mp,
    const float* __restrict__ Lp,
    int M, int N, int K, int Kc)
{
    __shared__ __align__(16) u16 SS[(TERMS == 3 ? 4 : 2) * 2048];
    u16* const AhS = SS;
    u16* const BhS = SS + 2048;
    u16* const AlS = SS + 4096;   // TERMS==3 only
    u16* const BlS = SS + 6144;
    const int tid = threadIdx.x;
    const int bn = blockIdx.x * 64, bm = blockIdx.y * 64;
    const int kb = blockIdx.z * Kc;
    const int r = tid >> 2, cch = tid & 3;
    const int widx = r * 32 + ((cch ^ ((r >> 1) & 3)) << 3);
    const int w = tid >> 6, lane = tid & 63;
    const int wm = w >> 1, wn = w & 1;
    const int lr = lane & 15, lc = lane >> 4;
    const int ar0 = wm * 32 + lr, ar1 = ar0 + 16;
    const int nr0 = wn * 32 + lr, nr1 = nr0 + 16;
    const int ai0 = ar0 * 32 + ((lc ^ ((ar0 >> 1) & 3)) << 3);
    const int ai1 = ar1 * 32 + ((lc ^ ((ar1 >> 1) & 3)) << 3);
    const int bi0 = nr0 * 32 + ((lc ^ ((nr0 >> 1) & 3)) << 3);
    const int bi1 = nr1 * 32 + ((lc ^ ((nr1 >> 1) & 3)) << 3);

    f4v acc00 = {0.f, 0.f, 0.f, 0.f}, acc01 = acc00, acc10 = acc00, acc11 = acc00;

    const int gr = bm + r;
    const float* apf = (const float*)A + (size_t)gr * K + kb + cch * 8;
    const u16*   aph = (const u16*)A + (size_t)gr * K + kb + cch * 8;
    const u16*   apl = Al2 ? Al2 + (size_t)gr * K + kb + cch * 8 : (const u16*)0;
    const u16* bhp = Bh + (size_t)(bn + r) * K + kb + cch * 8;
    const u16* blp = (TERMS == 3) ? Bl + (size_t)(bn + r) * K + kb + cch * 8
                                  : (const u16*)0;

    // LNS prologue: precomputed stats for row gr
    float mu_r = 0.f, rs_r = 1.f;
    if (LNS) {
        if (gr < M) { mu_r = Mp[gr]; rs_r = Lp[gr]; }
    }

    // FATT prologue: softmax-combine factors for row gr, heads kb/32, kb/32+1
    float fac_s[FATT ? NSPLIT : 1][FATT ? 2 : 1];
    float invL[FATT ? 2 : 1];
    if (FATT) {
        if (gr < M) {
#pragma unroll
            for (int hh = 0; hh < 2; ++hh) {
                int h = (kb >> 5) + hh;
                float ms[NSPLIT], ls[NSPLIT], Mx = -1e30f;
#pragma unroll
                for (int s = 0; s < NSPLIT; ++s) {
                    ms[s] = Mp[((size_t)s * SEQ_PAD + gr) * NHEAD + h];
                    ls[s] = Lp[((size_t)s * SEQ_PAD + gr) * NHEAD + h];
                    Mx = fmaxf(Mx, ms[s]);
                }
                float L = 0.f;
#pragma unroll
                for (int s = 0; s < NSPLIT; ++s) {
                    float f = __expf(ms[s] - Mx);
                    fac_s[s][hh] = f;
                    L += ls[s] * f;
                }
                invL[hh] = 1.f / L;
            }
        } else {
#pragma unroll
            for (int hh = 0; hh < 2; ++hh) {
                invL[hh] = 0.f;
#pragma unroll
                for (int s = 0; s < NSPLIT; ++s) fac_s[s][hh] = 0.f;
            }
        }
    }

    for (int k0 = 0; k0 < Kc; k0 += 32) {
        s8v hv = {0, 0, 0, 0, 0, 0, 0, 0}, lv = hv;
        if (FATT) {
            if (gr < M) {
                int hh = k0 >> 5;
                float v[8] = {0.f, 0.f, 0.f, 0.f, 0.f, 0.f, 0.f, 0.f};
#pragma unroll
                for (int s = 0; s < NSPLIT; ++s) {
                    const float* op = (const float*)A
                        + ((size_t)s * SEQ_PAD + gr) * 256 + kb + k0 + cch * 8;
                    float4 x0 = *(const float4*)op;
                    float4 x1 = *(const float4*)(op + 4);
                    float f = fac_s[s][hh];
                    v[0] += f * x0.x; v[1] += f * x0.y;
                    v[2] += f * x0.z; v[3] += f * x0.w;
                    v[4] += f * x1.x; v[5] += f * x1.y;
                    v[6] += f * x1.z; v[7] += f * x1.w;
                }
                float il = invL[hh];
#pragma unroll
                for (int e = 0; e < 8; ++e) hv[e] = (short)f2bf(v[e] * il);
            }
        } else if (APRE) {
            if (gr < M) {
                hv = *(const s8v*)aph;
                if (TERMS == 3) lv = *(const s8v*)apl;
            }
        } else {
            float v[8] = {0.f, 0.f, 0.f, 0.f, 0.f, 0.f, 0.f, 0.f};
            if (gr < M) {
                float4 x0 = *(const float4*)apf;
                float4 x1 = *(const float4*)(apf + 4);
                v[0] = x0.x; v[1] = x0.y; v[2] = x0.z; v[3] = x0.w;
                v[4] = x1.x; v[5] = x1.y; v[6] = x1.z; v[7] = x1.w;
            }
#pragma unroll
            for (int e = 0; e < 8; ++e) {
                float vv = LNS ? (v[e] - mu_r) * rs_r : v[e];
                u16 h = f2bf(vv);
                hv[e] = (short)h;
                if (TERMS == 3) lv[e] = (short)f2bf(vv - bf2f(h));
            }
        }
        *(s8v*)&AhS[widx] = hv;
        *(s8v*)&BhS[widx] = *(const s8v*)bhp;
        if (TERMS == 3) {
            *(s8v*)&AlS[widx] = lv;
            *(s8v*)&BlS[widx] = *(const s8v*)blp;
        }
        __syncthreads();

        s8v a0h = *(s8v*)&AhS[ai0], a1h = *(s8v*)&AhS[ai1];
        s8v b0h = *(s8v*)&BhS[bi0], b1h = *(s8v*)&BhS[bi1];
        acc00 = __builtin_amdgcn_mfma_f32_16x16x32_bf16(a0h, b0h, acc00, 0, 0, 0);
        acc01 = __builtin_amdgcn_mfma_f32_16x16x32_bf16(a0h, b1h, acc01, 0, 0, 0);
        acc10 = __builtin_amdgcn_mfma_f32_16x16x32_bf16(a1h, b0h, acc10, 0, 0, 0);
        acc11 = __builtin_amdgcn_mfma_f32_16x16x32_bf16(a1h, b1h, acc11, 0, 0, 0);
        if (TERMS == 3) {
            s8v a0l = *(s8v*)&AlS[ai0], a1l = *(s8v*)&AlS[ai1];
            s8v b0l = *(s8v*)&BlS[bi0], b1l = *(s8v*)&BlS[bi1];
            acc00 = __builtin_amdgcn_mfma_f32_16x16x32_bf16(a0h, b0l, acc00, 0, 0, 0);
            acc00 = __builtin_amdgcn_mfma_f32_16x16x32_bf16(a0l, b0h, acc00, 0, 0, 0);
            acc01 = __builtin_amdgcn_mfma_f32_16x16x32_bf16(a0h, b1l, acc01, 0, 0, 0);
            acc01 = __builtin_amdgcn_mfma_f32_16x16x32_bf16(a0l, b1h, acc01, 0, 0, 0);
            acc10 = __builtin_amdgcn_mfma_f32_16x16x32_bf16(a1h, b0l, acc10, 0, 0, 0);
            acc10 = __builtin_amdgcn_mfma_f32_16x16x32_bf16(a1l, b0h, acc10, 0, 0, 0);
            acc11 = __builtin_amdgcn_mfma_f32_16x16x32_bf16(a1h, b1l, acc11, 0, 0, 0);
            acc11 = __builtin_amdgcn_mfma_f32_16x16x32_bf16(a1l, b1h, acc11, 0, 0, 0);
        }
        __syncthreads();
        apf += 32; aph += 32; if (TERMS == 3) apl += 32;
        bhp += 32; if (TERMS == 3) blp += 32;
    }

#pragma unroll
    for (int fg = 0; fg < 4; ++fg) {
        int f = fg >> 1, g = fg & 1;
        f4v a = (fg == 0) ? acc00 : (fg == 1) ? acc01 : (fg == 2) ? acc10 : acc11;
        int col = bn + wn * 32 + g * 16 + lr;
        int row0 = bm + wm * 32 + f * 16 + lc * 4;
#pragma unroll
        for (int j = 0; j < 4; ++j) {
            int rr = row0 + j;
            if (rr < M) {
                float vv = a[j];
                if (ATOM) {
                    if (bias && blockIdx.z == 0) vv += bias[col];
                    atomicAdd(&C[(size_t)rr * N + col], vv);
                } else {
                    if (bias) vv += bias[col];
                    if (ACT == 1) vv = 0.5f * vv * (1.0f + erff(vv * 0.70710678118654752f));
                    if (RES) vv += Rsd[(size_t)rr * N + col];
                    if (OB == 1) ((u16*)C)[(size_t)rr * N + col] = f2bf(vv);
                    else         C[(size_t)rr * N + col] = vv;
                }
            }
        }
    }
}

// seq init: row 0 = class token, rows 1.. = embedding bias (atomic GEMM base)
__global__ void init_seq(float* __restrict__ seq, const float* __restrict__ bias,
                         const float* __restrict__ cls)
{
    int row = blockIdx.x;
    int t = threadIdx.x;
    seq[(size_t)row * 256 + t] = (row == 0) ? cls[t] : bias[t];
}

__global__ void pad_zero_u32(unsigned* __restrict__ p, int n)
{
    int i = blockIdx.x * 256 + threadIdx.x;
    if (i < n) p[i] = 0u;
}

__global__ void vecmat256(const float* __restrict__ v, const float* __restrict__ W,
                          float* __restrict__ out)
{
    int n = threadIdx.x;
    float acc = 0.f;
    for (int k = 0; k < 256; ++k) acc += v[k] * W[k * 256 + n];
    out[n] = acc;
}

// ---------------------------------------------------------------------------
// GAT pieces
// ---------------------------------------------------------------------------
__global__ void gat_init(float* __restrict__ emax, float* __restrict__ denom,
                         int* __restrict__ deg)
{
    int i = blockIdx.x * 256 + threadIdx.x;
    emax[i] = -1e30f;
    denom[i] = 0.f;
    deg[i] = 0;
}

__global__ __launch_bounds__(256) void gat_scores(
    const u16* __restrict__ WH, const float* __restrict__ a_src,
    const float* __restrict__ a_dst, float* __restrict__ s_src,
    float* __restrict__ s_dst)
{
    int gid = blockIdx.x * 256 + threadIdx.x;
    int node = gid >> 6;
    int lane = gid & 63;
    uint2 rv = *(const uint2*)(WH + (size_t)node * D_MODEL + (lane << 2));
    float d0 = __uint_as_float(rv.x << 16);
    float d1 = __uint_as_float(rv.x & 0xffff0000u);
    float d2 = __uint_as_float(rv.y << 16);
    float d3 = __uint_as_float(rv.y & 0xffff0000u);
    float4 asv = *(const float4*)(a_src + (lane << 2));
    float4 adv = *(const float4*)(a_dst + (lane << 2));
    float as = d0 * asv.x + d1 * asv.y + d2 * asv.z + d3 * asv.w;
    float ad = d0 * adv.x + d1 * adv.y + d2 * adv.z + d3 * adv.w;
#pragma unroll
    for (int off = 32; off; off >>= 1) {
        as += __shfl_down(as, off);
        ad += __shfl_down(ad, off);
    }
    if (lane == 0) { s_src[node] = as; s_dst[node] = ad; }
}

__device__ __forceinline__ void atomicMaxFloat(float* addr, float val)
{
    int* ai = (int*)addr;
    int old = __float_as_int(*addr);
    while (__int_as_float(old) < val) {
        int prev = atomicCAS(ai, old, __float_as_int(val));
        if (prev == old) break;
        old = prev;
    }
}

__global__ void edge_pass1(const int* __restrict__ ei, const float* __restrict__ s_src,
                           const float* __restrict__ s_dst, float* __restrict__ e_buf,
                           float* __restrict__ emax, int* __restrict__ deg)
{
    int j = blockIdx.x * 256 + threadIdx.x;
    if (j >= EE_EDGES) return;
    int s, d;
    if (j < E_EDGES) { s = ei[j]; d = ei[E_EDGES + j]; }
    else { s = d = j - E_EDGES; }
    float e = s_src[s] + s_dst[d];
    e = (e > 0.f) ? e : 0.2f * e;
    e_buf[j] = e;
    atomicMaxFloat(&emax[d], e);
    atomicAdd(&deg[d], 1);
}

__global__ void scan1(const int* __restrict__ in, int* __restrict__ out_excl,
                      int* __restrict__ bsum)
{
    __shared__ int s[256];
    int t = threadIdx.x;
    int i = blockIdx.x * 256 + t;
    int v = in[i];
    s[t] = v;
    __syncthreads();
    for (int off = 1; off < 256; off <<= 1) {
        int u = (t >= off) ? s[t - off] : 0;
        __syncthreads();
        s[t] += u;
        __syncthreads();
    }
    out_excl[i] = s[t] - v;
    if (t == 255) bsum[blockIdx.x] = s[255];
}

__global__ void scan2(int* __restrict__ bsum)
{
    __shared__ int s[256];
    int t = threadIdx.x;
    int v = bsum[t];
    s[t] = v;
    __syncthreads();
    for (int off = 1; off < 256; off <<= 1) {
        int u = (t >= off) ? s[t - off] : 0;
        __syncthreads();
        s[t] += u;
        __syncthreads();
    }
    bsum[t] = s[t] - v;
}

__global__ void scan3(int* __restrict__ offs, const int* __restrict__ bsum,
                      int* __restrict__ cur)
{
    int i = blockIdx.x * 256 + threadIdx.x;
    int v = offs[i] + bsum[blockIdx.x];
    offs[i] = v;
    cur[i] = v;
}

__global__ void edge_pass2(const int* __restrict__ ei, const float* __restrict__ e_buf,
                           const float* __restrict__ emax, float* __restrict__ denom,
                           int* __restrict__ cur, int* __restrict__ csr_src,
                           float* __restrict__ csr_w)
{
    int j = blockIdx.x * 256 + threadIdx.x;
    if (j >= EE_EDGES) return;
    int s, d;
    if (j < E_EDGES) { s = ei[j]; d = ei[E_EDGES + j]; }
    else { s = d = j - E_EDGES; }
    float ee = __expf(e_buf[j] - emax[d]);
    atomicAdd(&denom[d], ee);
    int pos = atomicAdd(&cur[d], 1);
    csr_src[pos] = s;
    csr_w[pos] = ee;
}

// bf16 WH gather, 4-way unrolled (4 independent gathers in flight)
__global__ __launch_bounds__(256) void gat_aggregate(
    const u16* __restrict__ WH, const int* __restrict__ csr_src,
    const float* __restrict__ csr_w, const int* __restrict__ offs,
    const int* __restrict__ deg, const float* __restrict__ denom,
    const float* __restrict__ b_gat, u16* __restrict__ hH)
{
    int gid = blockIdx.x * 256 + threadIdx.x;
    int node = gid >> 6;
    int lane = gid & 63;
    float a0 = 0.f, a1 = 0.f, a2 = 0.f, a3 = 0.f;
    int s0 = offs[node], e0 = s0 + deg[node];
    int k = s0;
    for (; k + 4 <= e0; k += 4) {
        int i0 = csr_src[k], i1 = csr_src[k + 1];
        int i2 = csr_src[k + 2], i3 = csr_src[k + 3];
        float w0 = csr_w[k], w1 = csr_w[k + 1];
        float w2 = csr_w[k + 2], w3 = csr_w[k + 3];
        uint2 r0 = *(const uint2*)(WH + (size_t)i0 * D_MODEL + (lane << 2));
        uint2 r1 = *(const uint2*)(WH + (size_t)i1 * D_MODEL + (lane << 2));
        uint2 r2 = *(const uint2*)(WH + (size_t)i2 * D_MODEL + (lane << 2));
        uint2 r3 = *(const uint2*)(WH + (size_t)i3 * D_MODEL + (lane << 2));
        a0 += w0 * __uint_as_float(r0.x << 16) + w1 * __uint_as_float(r1.x << 16)
            + w2 * __uint_as_float(r2.x << 16) + w3 * __uint_as_float(r3.x << 16);
        a1 += w0 * __uint_as_float(r0.x & 0xffff0000u) + w1 * __uint_as_float(r1.x & 0xffff0000u)
            + w2 * __uint_as_float(r2.x & 0xffff0000u) + w3 * __uint_as_float(r3.x & 0xffff0000u);
        a2 += w0 * __uint_as_float(r0.y << 16) + w1 * __uint_as_float(r1.y << 16)
            + w2 * __uint_as_float(r2.y << 16) + w3 * __uint_as_float(r3.y << 16);
        a3 += w0 * __uint_as_float(r0.y & 0xffff0000u) + w1 * __uint_as_float(r1.y & 0xffff0000u)
            + w2 * __uint_as_float(r2.y & 0xffff0000u) + w3 * __uint_as_float(r3.y & 0xffff0000u);
    }
    for (; k < e0; ++k) {
        int src = csr_src[k];
        float alpha = csr_w[k];
        uint2 rv = *(const uint2*)(WH + (size_t)src * D_MODEL + (lane << 2));
        a0 += alpha * __uint_as_float(rv.x << 16);
        a1 += alpha * __uint_as_float(rv.x & 0xffff0000u);
        a2 += alpha * __uint_as_float(rv.y << 16);
        a3 += alpha * __uint_as_float(rv.y & 0xffff0000u);
    }
    float inv = 1.0f / denom[node];
    float4 bg = *(const float4*)(b_gat + (lane << 2));
    float v0 = a0 * inv + bg.x, v1 = a1 * inv + bg.y;
    float v2 = a2 * inv + bg.z, v3 = a3 * inv + bg.w;
    uint2 ho;
    ho.x = (unsigned)f2bf(v0) | ((unsigned)f2bf(v1) << 16);
    ho.y = (unsigned)f2bf(v2) | ((unsigned)f2bf(v3) << 16);
    *(uint2*)(hH + (size_t)node * D_MODEL + (lane << 2)) = ho;
}

// ---------------------------------------------------------------------------
// Split-KV MFMA flash attention. Grid (33, 8, NSPLIT).
// ---------------------------------------------------------------------------
__global__ __launch_bounds__(256) void mfma_attn_split(
    const u16* __restrict__ QKV, float* __restrict__ Opart,
    float* __restrict__ Mpart, float* __restrict__ Lpart)
{
    __shared__ __align__(16) u16 Ks[64 * 32];
    __shared__ __align__(16) u16 Vt[32 * 72];
    __shared__ __align__(16) u16 Ps[4 * 16 * 72];
    const int tid = threadIdx.x;
    const int w = tid >> 6, lane = tid & 63;
    const int g = lane >> 4, ql = lane & 15;
    const int h = blockIdx.y;
    const int sp = blockIdx.z;
    const int t0 = (33 * sp) / NSPLIT, t1 = (33 * (sp + 1)) / NSPLIT;
    const int qbase = blockIdx.x * 64 + w * 16;
    const float scale = 0.17677669529663687f;

    int qrow = qbase + ql; if (qrow > SEQ_LEN - 1) qrow = SEQ_LEN - 1;
    const s8v qfrag = *(const s8v*)(QKV + (size_t)qrow * 768 + h * 32 + g * 8);

    f4v o0 = {0.f, 0.f, 0.f, 0.f}, o1 = o0;
    float m[4], l[4];
#pragma unroll
    for (int r = 0; r < 4; ++r) { m[r] = -1e30f; l[r] = 0.f; }

    const int sr = tid >> 2, sc_ = tid & 3;
    const int kslot = sc_ ^ ((sr >> 1) & 3);
    u16* const psw = &Ps[w * 1152];

    for (int t = t0; t < t1; ++t) {
        __syncthreads();
        {
            int grow = t * 64 + sr;
            const u16* kp = QKV + (size_t)grow * 768 + 256 + h * 32 + sc_ * 8;
            s8v kvv = *(const s8v*)kp;
            s8v vvv = *(const s8v*)(kp + 256);
            *(s8v*)&Ks[sr * 32 + kslot * 8] = kvv;
#pragma unroll
            for (int e = 0; e < 8; ++e) Vt[(sc_ * 8 + e) * 72 + sr] = (u16)vvv[e];
        }
        __syncthreads();

        f4v s[4];
        const f4v zz = {0.f, 0.f, 0.f, 0.f};
#pragma unroll
        for (int c = 0; c < 4; ++c) {
            int kvloc = c * 16 + ql;
            s8v kf = *(s8v*)&Ks[kvloc * 32 + ((g ^ ((kvloc >> 1) & 3)) << 3)];
            s[c] = __builtin_amdgcn_mfma_f32_16x16x32_bf16(qfrag, kf, zz, 0, 0, 0);
            int kvg = t * 64 + kvloc;
            bool valid = (kvg < SEQ_LEN);
#pragma unroll
            for (int r = 0; r < 4; ++r)
                s[c][r] = valid ? s[c][r] * scale : -1e30f;
        }

        float mloc[4];
#pragma unroll
        for (int r = 0; r < 4; ++r) {
            float v = fmaxf(fmaxf(s[0][r], s[1][r]), fmaxf(s[2][r], s[3][r]));
            v = fmaxf(v, __shfl_xor(v, 1));
            v = fmaxf(v, __shfl_xor(v, 2));
            v = fmaxf(v, __shfl_xor(v, 4));
            v = fmaxf(v, __shfl_xor(v, 8));
            mloc[r] = v;
        }
        float fac[4];
#pragma unroll
        for (int r = 0; r < 4; ++r) {
            float mn = fmaxf(m[r], mloc[r]);
            fac[r] = __expf(m[r] - mn);
            m[r] = mn;
        }
#pragma unroll
        for (int c = 0; c < 4; ++c)
#pragma unroll
            for (int r = 0; r < 4; ++r)
                s[c][r] = __expf(s[c][r] - m[r]);
#pragma unroll
        for (int r = 0; r < 4; ++r) {
            float ls = s[0][r] + s[1][r] + s[2][r] + s[3][r];
            ls += __shfl_xor(ls, 1);
            ls += __shfl_xor(ls, 2);
            ls += __shfl_xor(ls, 4);
            ls += __shfl_xor(ls, 8);
            l[r] = l[r] * fac[r] + ls;
            o0[r] *= fac[r];
            o1[r] *= fac[r];
        }

#pragma unroll
        for (int c = 0; c < 4; ++c)
#pragma unroll
            for (int r = 0; r < 4; ++r)
                psw[(g * 4 + r) * 72 + c * 16 + ql] = f2bf(s[c][r]);

#pragma unroll
        for (int kch = 0; kch < 2; ++kch) {
            s8v pf = *(s8v*)&psw[ql * 72 + kch * 32 + g * 8];
            s8v v0 = *(s8v*)&Vt[ql * 72 + kch * 32 + g * 8];
            s8v v1 = *(s8v*)&Vt[(16 + ql) * 72 + kch * 32 + g * 8];
            o0 = __builtin_amdgcn_mfma_f32_16x16x32_bf16(pf, v0, o0, 0, 0, 0);
            o1 = __builtin_amdgcn_mfma_f32_16x16x32_bf16(pf, v1, o1, 0, 0, 0);
        }
    }

#pragma unroll
    for (int r = 0; r < 4; ++r) {
        int q = qbase + g * 4 + r;
        if (q < SEQ_LEN) {
            size_t base = ((size_t)sp * SEQ_PAD + q) * 256 + h * 32;
            Opart[base + ql] = o0[r];
            Opart[base + 16 + ql] = o1[r];
            if (ql == 0) {
                Mpart[((size_t)sp * SEQ_PAD + q) * NHEAD + h] = m[r];
                Lpart[((size_t)sp * SEQ_PAD + q) * NHEAD + h] = l[r];
            }
        }
    }
}

__global__ void cls_head(const float* __restrict__ seq, const float* __restrict__ W,
                         const float* __restrict__ b, float* __restrict__ out)
{
    __shared__ float s[256];
    int t = threadIdx.x;
    s[t] = seq[t];
    __syncthreads();
    if (t < NCLS) {
        float acc = b[t];
        for (int k = 0; k < 256; ++k) acc += s[k] * W[k * NCLS + t];
        out[t] = acc;
    }
}

// ---------------------------------------------------------------------------
extern "C" void kernel_launch(void* const* d_in, const int* in_sizes, int n_in,
                              void* d_out, int out_size, void* d_ws, size_t ws_size,
                              hipStream_t stream)
{
    (void)in_sizes; (void)n_in; (void)out_size; (void)ws_size;
    const float* x       = (const float*)d_in[0];
    const int*   ei      = (const int*)d_in[1];
    const float* W_in    = (const float*)d_in[2];
    const float* b_in    = (const float*)d_in[3];
    const float* W_gat   = (const float*)d_in[4];
    const float* a_src   = (const float*)d_in[5];
    const float* a_dst   = (const float*)d_in[6];
    const float* b_gat   = (const float*)d_in[7];
    const float* W_emb   = (const float*)d_in[8];
    const float* b_emb   = (const float*)d_in[9];
    const float* cls_tok = (const float*)d_in[10];
    const float* ln1_s   = (const float*)d_in[11];
    const float* ln1_b   = (const float*)d_in[12];
    const float* Wqkv    = (const float*)d_in[13];
    const float* bqkv    = (const float*)d_in[14];
    const float* Wproj   = (const float*)d_in[15];
    const float* bproj   = (const float*)d_in[16];
    const float* ln2_s   = (const float*)d_in[17];
    const float* ln2_b   = (const float*)d_in[18];
    const float* W1      = (const float*)d_in[19];
    const float* b1      = (const float*)d_in[20];
    const float* W2      = (const float*)d_in[21];
    const float* b2      = (const float*)d_in[22];
    const float* W_cls   = (const float*)d_in[23];
    const float* b_cls   = (const float*)d_in[24];
    float* out = (float*)d_out;

    // -------- workspace layout --------
    float* ws = (float*)d_ws;
    u16*   bufWHu = (u16*)ws;                  // N x 256 bf16 (GAT phase)
    float* seqb  = ws;                         // 524544 f (transformer phase)
    u16*   QKVb  = (u16*)(ws + 1049088);       // 2112*768 u16
    u16*   MLPHh = (u16*)(ws + 2384640);       // 2049*1024 u16
    float* qkvBias = ws + 3500000;             // 8*768
    float* w1Bias  = qkvBias + 8 * 768;        // 8*1024
    float* muA     = w1Bias + 8 * 1024;        // 2112
    float* rsA     = muA + 2112;               // 2112
    u16*   wreg  = (u16*)(ws + 5500000);       // weights
    u16* embh  = wreg;
    u16* embl  = wreg + 2097152;
    u16* qkvh  = wreg + 4194304;
    u16* qkvl  = wreg + 5767168;
    u16* projh = wreg + 7340032;
    u16* projl = wreg + 7864320;
    u16* w1h   = wreg + 8388608;
    u16* w1l   = wreg + 10485760;
    u16* w2h   = wreg + 12582912;
    u16* w2l   = wreg + 14680064;
    // region B: hH (GAT output) — dead after embedding; attn partials alias it
    u16*   hH    = (u16*)(ws + 16777216);
    float* Opart = ws + 16777216;              // NSPLIT*2112*256 f
    float* Mpart = Opart + (size_t)NSPLIT * SEQ_PAD * 256;
    float* Lpart = Mpart + (size_t)NSPLIT * SEQ_PAD * NHEAD;
    float* sm    = ws + 2 * 16777216;
    float* s_src = sm;
    float* s_dst = sm + 65536;
    float* emaxb = sm + 2 * 65536;
    float* denom = sm + 3 * 65536;
    float* e_buf = sm + 4 * 65536;
    float* csr_w = e_buf + 589824;
    float* Wc    = csr_w + 589824;
    float* bc    = Wc + 32768;
    int*   deg     = (int*)(bc + 256);
    int*   offs    = deg + 65536;
    int*   cur     = offs + 65536;
    int*   bsum    = cur + 65536;
    int*   csr_src = bsum + 256;
    u16*   wgTh = (u16*)(csr_src + 589824);
    u16*   wgTl = wgTh + 65536;
    u16*   wcTh = wgTh + 131072;
    u16*   wcTl = wcTh + 32768;

    // -------- GAT preprocessing --------
    gat_init<<<256, 256, 0, stream>>>(emaxb, denom, deg);
    prep_weight<<<dim3(4, 4, 1), 256, 0, stream>>>(W_gat, wgTh, wgTl, 256, 256,
                                                   0, 0, 1, nullptr);
    hgemm<0,0,0,0,0,3,0,0><<<dim3(4, 2, 1), 256, 0, stream>>>(
        W_in, nullptr, wgTh, wgTl, nullptr, nullptr, Wc, nullptr, nullptr,
        128, 256, 256, 256);
    vecmat256<<<1, 256, 0, stream>>>(b_in, W_gat, bc);
    prep_weight<<<dim3(2, 4, 1), 256, 0, stream>>>(Wc, wcTh, wcTl, 128, 256,
                                                   0, 0, 0, nullptr);
    hgemm<0,0,0,1,0,1,0,0><<<dim3(4, 1024, 1), 256, 0, stream>>>(
        x, nullptr, wcTh, nullptr, bc, nullptr, (float*)bufWHu, nullptr, nullptr,
        N_NODES, 256, 128, 128);
    gat_scores<<<16384, 256, 0, stream>>>(bufWHu, a_src, a_dst, s_src, s_dst);
    edge_pass1<<<EE_EDGES / 256, 256, 0, stream>>>(ei, s_src, s_dst, e_buf, emaxb, deg);
    scan1<<<256, 256, 0, stream>>>(deg, offs, bsum);
    scan2<<<1, 256, 0, stream>>>(bsum);
    scan3<<<256, 256, 0, stream>>>(offs, bsum, cur);
    edge_pass2<<<EE_EDGES / 256, 256, 0, stream>>>(ei, e_buf, emaxb, denom, cur,
                                                   csr_src, csr_w);
    gat_aggregate<<<16384, 256, 0, stream>>>(bufWHu, csr_src, csr_w, offs, deg,
                                             denom, b_gat, hH);

    // -------- weight prep (LN gamma folded into qkv/w1; beta into bias) ----
    prep_weight<<<dim3(128, 4, 1), 256, 0, stream>>>(W_emb, embh, embl, 8192, 256,
                                                     0, 0, 0, nullptr);
    prep_weight<<<dim3(4, 12, 8), 256, 0, stream>>>(Wqkv, qkvh, qkvl, 256, 768,
                                                    196608, 196608, 0, ln1_s);
    prep_weight<<<dim3(4, 4, 8), 256, 0, stream>>>(Wproj, projh, projl, 256, 256,
                                                   65536, 65536, 0, nullptr);
    prep_weight<<<dim3(4, 16, 8), 256, 0, stream>>>(W1, w1h, w1l, 256, 1024,
                                                    262144, 262144, 0, ln2_s);
    prep_weight<<<dim3(16, 4, 8), 256, 0, stream>>>(W2, w2h, w2l, 1024, 256,
                                                    262144, 262144, 0, nullptr);
    bias_fold<<<dim3(3, 8), 256, 0, stream>>>(ln1_b, Wqkv, bqkv, qkvBias, 768, 196608);
    bias_fold<<<dim3(4, 8), 256, 0, stream>>>(ln2_b, W1, b1, w1Bias, 1024, 262144);

    // -------- token embedding (split-K x8, atomic onto bias/cls-seeded seq) --
    init_seq<<<SEQ_LEN, 256, 0, stream>>>(seqb, b_emb, cls_tok);
    hgemm<0,0,1,0,1,1,0,0><<<dim3(4, 32, 8), 256, 0, stream>>>(
        (const void*)hH, nullptr, embh, nullptr, nullptr, nullptr, seqb + 256,
        nullptr, nullptr, 2048, 256, 8192, 1024);

    pad_zero_u32<<<95, 256, 0, stream>>>(
        (unsigned*)(QKVb + (size_t)SEQ_LEN * 768), (SEQ_PAD - SEQ_LEN) * 768 / 2);

    // -------- transformer layers (LN via precomputed stats) --------
    for (int i = 0; i < 8; ++i) {
        ln_stats<<<513, 256, 0, stream>>>(seqb, muA, rsA);
        hgemm<0,0,0,1,0,1,0,1><<<dim3(12, 33, 1), 256, 0, stream>>>(
            (const void*)seqb, nullptr, qkvh + (size_t)i * 196608, nullptr,
            qkvBias + (size_t)i * 768, nullptr, (float*)QKVb, muA, rsA,
            SEQ_LEN, 768, 256, 256);
        mfma_attn_split<<<dim3(33, NHEAD, NSPLIT), 256, 0, stream>>>(
            QKVb, Opart, Mpart, Lpart);
        hgemm<0,0,1,0,0,1,1,0><<<dim3(4, 33, 4), 256, 0, stream>>>(
            (const void*)Opart, nullptr, projh + (size_t)i * 65536, nullptr,
            bproj + (size_t)i * 256, nullptr, seqb, Mpart, Lpart,
            SEQ_LEN, 256, 256, 64);
        ln_stats<<<513, 256, 0, stream>>>(seqb, muA, rsA);
        hgemm<1,0,0,1,0,1,0,1><<<dim3(16, 33, 1), 256, 0, stream>>>(
            (const void*)seqb, nullptr, w1h + (size_t)i * 262144, nullptr,
            w1Bias + (size_t)i * 1024, nullptr, (float*)MLPHh, muA, rsA,
            SEQ_LEN, 1024, 256, 256);
        hgemm<0,0,1,0,1,1,0,0><<<dim3(4, 33, 4), 256, 0, stream>>>(
            (const void*)MLPHh, nullptr, w2h + (size_t)i * 262144, nullptr,
            b2 + (size_t)i * 256, nullptr, seqb, nullptr, nullptr,
            SEQ_LEN, 256, 1024, 256);
    }

    // -------- classifier head --------
    cls_head<<<1, 256, 0, stream>>>(seqb, W_cls, b_cls, out);
}

// Round 10
// 960.084 us; speedup vs baseline: 1.1689x; 1.1689x over previous
//
#include <hip/hip_runtime.h>
#include <math.h>

#define N_NODES 65536
#define F_IN 128
#define D_MODEL 256
#define E_EDGES 524288
#define EE_EDGES 589824   /* E + N self loops */
#define SEQ_LEN 2049
#define SEQ_PAD 2112      /* 33*64 */
#define NHEAD 8
#define HDIM 32
#define NCLS 10
#define NSPLIT 4          /* attention KV splits */

typedef unsigned short u16;
typedef __attribute__((ext_vector_type(8))) short s8v;   // 8 x bf16 (4 VGPR)
typedef __attribute__((ext_vector_type(4))) float f4v;   // 4 x f32 acc

__device__ __forceinline__ u16 f2bf(float f)
{
    union { float f; unsigned u; } v; v.f = f;
    unsigned r = v.u + 0x7FFF + ((v.u >> 16) & 1);
    return (u16)(r >> 16);
}
__device__ __forceinline__ float bf2f(u16 h)
{
    union { unsigned u; float f; } v; v.u = ((unsigned)h) << 16;
    return v.f;
}

// ---------------------------------------------------------------------------
// prep: W [K,N] fp32 (row-major) -> Oh (and optionally Ol) [N,K] bf16
// ---------------------------------------------------------------------------
__global__ __launch_bounds__(256) void prep_weight(
    const float* __restrict__ W, u16* __restrict__ Oh, u16* __restrict__ Ol,
    int K, int N, long long strideW, long long strideO, int write_lo)
{
    const float* Wz = W + (size_t)blockIdx.z * strideW;
    u16* Ohz = Oh + (size_t)blockIdx.z * strideO;
    u16* Olz = Ol + (size_t)blockIdx.z * strideO;
    __shared__ u16 th[64][68];
    __shared__ u16 tl[64][68];
    int kb = blockIdx.x * 64, nb = blockIdx.y * 64;
    int t = threadIdx.x;
    int kr = t >> 4, nc = (t & 15) * 4;
#pragma unroll
    for (int i = 0; i < 4; ++i) {
        int k = kr + i * 16;
        float4 v = *(const float4*)(Wz + (size_t)(kb + k) * N + nb + nc);
        float vv[4] = {v.x, v.y, v.z, v.w};
#pragma unroll
        for (int e = 0; e < 4; ++e) {
            u16 h = f2bf(vv[e]);
            th[k][nc + e] = h;
            if (write_lo) tl[k][nc + e] = f2bf(vv[e] - bf2f(h));
        }
    }
    __syncthreads();
    int nr = t >> 4, kc = (t & 15) * 4;
#pragma unroll
    for (int i = 0; i < 4; ++i) {
        int n = nr + i * 16;
        uint2 oh;
        oh.x = (unsigned)th[kc + 0][n] | ((unsigned)th[kc + 1][n] << 16);
        oh.y = (unsigned)th[kc + 2][n] | ((unsigned)th[kc + 3][n] << 16);
        *(uint2*)(Ohz + (size_t)(nb + n) * K + kb + kc) = oh;
        if (write_lo) {
            uint2 ol;
            ol.x = (unsigned)tl[kc + 0][n] | ((unsigned)tl[kc + 1][n] << 16);
            ol.y = (unsigned)tl[kc + 2][n] | ((unsigned)tl[kc + 3][n] << 16);
            *(uint2*)(Olz + (size_t)(nb + n) * K + kb + kc) = ol;
        }
    }
}

// ---------------------------------------------------------------------------
// bf16 MFMA GEMM. TERMS=3: hi/lo 3-term; TERMS=1: plain bf16.
// APRE=1: A bf16 pre-split. FATT=1: A = attention partials (Opart fp32,
//   combined on the fly with Mp/Lp; requires ATOM=1, Kc=64).
// OB=1: bf16 C. ATOM=1: fp32 atomicAdd into preinitialized C.
// ---------------------------------------------------------------------------
template<int ACT, int RES, int ATOM, int OB, int APRE, int TERMS, int FATT>
__global__ __launch_bounds__(256) void hgemm(
    const void* __restrict__ A, const u16* __restrict__ Al2,
    const u16* __restrict__ Bh, const u16* __restrict__ Bl,
    const float* __restrict__ bias, const float* __restrict__ Rsd,
    float* __restrict__ C, const float* __restrict__ Mp,
    const float* __restrict__ Lp,
    int M, int N, int K, int Kc)
{
    __shared__ __align__(16) u16 SS[(TERMS == 3 ? 4 : 2) * 2048];
    u16* const AhS = SS;
    u16* const BhS = SS + 2048;
    u16* const AlS = SS + 4096;   // TERMS==3 only
    u16* const BlS = SS + 6144;
    const int tid = threadIdx.x;
    const int bn = blockIdx.x * 64, bm = blockIdx.y * 64;
    const int kb = blockIdx.z * Kc;
    const int r = tid >> 2, cch = tid & 3;
    const int widx = r * 32 + ((cch ^ ((r >> 1) & 3)) << 3);
    const int w = tid >> 6, lane = tid & 63;
    const int wm = w >> 1, wn = w & 1;
    const int lr = lane & 15, lc = lane >> 4;
    const int ar0 = wm * 32 + lr, ar1 = ar0 + 16;
    const int nr0 = wn * 32 + lr, nr1 = nr0 + 16;
    const int ai0 = ar0 * 32 + ((lc ^ ((ar0 >> 1) & 3)) << 3);
    const int ai1 = ar1 * 32 + ((lc ^ ((ar1 >> 1) & 3)) << 3);
    const int bi0 = nr0 * 32 + ((lc ^ ((nr0 >> 1) & 3)) << 3);
    const int bi1 = nr1 * 32 + ((lc ^ ((nr1 >> 1) & 3)) << 3);

    f4v acc00 = {0.f, 0.f, 0.f, 0.f}, acc01 = acc00, acc10 = acc00, acc11 = acc00;

    const int gr = bm + r;
    const float* apf = (const float*)A + (size_t)gr * K + kb + cch * 8;
    const u16*   aph = (const u16*)A + (size_t)gr * K + kb + cch * 8;
    const u16*   apl = Al2 ? Al2 + (size_t)gr * K + kb + cch * 8 : (const u16*)0;
    const u16* bhp = Bh + (size_t)(bn + r) * K + kb + cch * 8;
    const u16* blp = (TERMS == 3) ? Bl + (size_t)(bn + r) * K + kb + cch * 8
                                  : (const u16*)0;

    // FATT prologue: softmax-combine factors for row gr, heads kb/32, kb/32+1
    float fac_s[FATT ? NSPLIT : 1][FATT ? 2 : 1];
    float invL[FATT ? 2 : 1];
    if (FATT) {
        if (gr < M) {
#pragma unroll
            for (int hh = 0; hh < 2; ++hh) {
                int h = (kb >> 5) + hh;
                float ms[NSPLIT], ls[NSPLIT], Mx = -1e30f;
#pragma unroll
                for (int s = 0; s < NSPLIT; ++s) {
                    ms[s] = Mp[((size_t)s * SEQ_PAD + gr) * NHEAD + h];
                    ls[s] = Lp[((size_t)s * SEQ_PAD + gr) * NHEAD + h];
                    Mx = fmaxf(Mx, ms[s]);
                }
                float L = 0.f;
#pragma unroll
                for (int s = 0; s < NSPLIT; ++s) {
                    float f = __expf(ms[s] - Mx);
                    fac_s[s][hh] = f;
                    L += ls[s] * f;
                }
                invL[hh] = 1.f / L;
            }
        } else {
#pragma unroll
            for (int hh = 0; hh < 2; ++hh) {
                invL[hh] = 0.f;
#pragma unroll
                for (int s = 0; s < NSPLIT; ++s) fac_s[s][hh] = 0.f;
            }
        }
    }

    for (int k0 = 0; k0 < Kc; k0 += 32) {
        s8v hv = {0, 0, 0, 0, 0, 0, 0, 0}, lv = hv;
        if (FATT) {
            if (gr < M) {
                int hh = k0 >> 5;
                float v[8] = {0.f, 0.f, 0.f, 0.f, 0.f, 0.f, 0.f, 0.f};
#pragma unroll
                for (int s = 0; s < NSPLIT; ++s) {
                    const float* op = (const float*)A
                        + ((size_t)s * SEQ_PAD + gr) * 256 + kb + k0 + cch * 8;
                    float4 x0 = *(const float4*)op;
                    float4 x1 = *(const float4*)(op + 4);
                    float f = fac_s[s][hh];
                    v[0] += f * x0.x; v[1] += f * x0.y;
                    v[2] += f * x0.z; v[3] += f * x0.w;
                    v[4] += f * x1.x; v[5] += f * x1.y;
                    v[6] += f * x1.z; v[7] += f * x1.w;
                }
                float il = invL[hh];
#pragma unroll
                for (int e = 0; e < 8; ++e) hv[e] = (short)f2bf(v[e] * il);
            }
        } else if (APRE) {
            if (gr < M) {
                hv = *(const s8v*)aph;
                if (TERMS == 3) lv = *(const s8v*)apl;
            }
        } else {
            float v[8] = {0.f, 0.f, 0.f, 0.f, 0.f, 0.f, 0.f, 0.f};
            if (gr < M) {
                float4 x0 = *(const float4*)apf;
                float4 x1 = *(const float4*)(apf + 4);
                v[0] = x0.x; v[1] = x0.y; v[2] = x0.z; v[3] = x0.w;
                v[4] = x1.x; v[5] = x1.y; v[6] = x1.z; v[7] = x1.w;
            }
#pragma unroll
            for (int e = 0; e < 8; ++e) {
                u16 h = f2bf(v[e]);
                hv[e] = (short)h;
                if (TERMS == 3) lv[e] = (short)f2bf(v[e] - bf2f(h));
            }
        }
        *(s8v*)&AhS[widx] = hv;
        *(s8v*)&BhS[widx] = *(const s8v*)bhp;
        if (TERMS == 3) {
            *(s8v*)&AlS[widx] = lv;
            *(s8v*)&BlS[widx] = *(const s8v*)blp;
        }
        __syncthreads();

        s8v a0h = *(s8v*)&AhS[ai0], a1h = *(s8v*)&AhS[ai1];
        s8v b0h = *(s8v*)&BhS[bi0], b1h = *(s8v*)&BhS[bi1];
        acc00 = __builtin_amdgcn_mfma_f32_16x16x32_bf16(a0h, b0h, acc00, 0, 0, 0);
        acc01 = __builtin_amdgcn_mfma_f32_16x16x32_bf16(a0h, b1h, acc01, 0, 0, 0);
        acc10 = __builtin_amdgcn_mfma_f32_16x16x32_bf16(a1h, b0h, acc10, 0, 0, 0);
        acc11 = __builtin_amdgcn_mfma_f32_16x16x32_bf16(a1h, b1h, acc11, 0, 0, 0);
        if (TERMS == 3) {
            s8v a0l = *(s8v*)&AlS[ai0], a1l = *(s8v*)&AlS[ai1];
            s8v b0l = *(s8v*)&BlS[bi0], b1l = *(s8v*)&BlS[bi1];
            acc00 = __builtin_amdgcn_mfma_f32_16x16x32_bf16(a0h, b0l, acc00, 0, 0, 0);
            acc00 = __builtin_amdgcn_mfma_f32_16x16x32_bf16(a0l, b0h, acc00, 0, 0, 0);
            acc01 = __builtin_amdgcn_mfma_f32_16x16x32_bf16(a0h, b1l, acc01, 0, 0, 0);
            acc01 = __builtin_amdgcn_mfma_f32_16x16x32_bf16(a0l, b1h, acc01, 0, 0, 0);
            acc10 = __builtin_amdgcn_mfma_f32_16x16x32_bf16(a1h, b0l, acc10, 0, 0, 0);
            acc10 = __builtin_amdgcn_mfma_f32_16x16x32_bf16(a1l, b0h, acc10, 0, 0, 0);
            acc11 = __builtin_amdgcn_mfma_f32_16x16x32_bf16(a1h, b1l, acc11, 0, 0, 0);
            acc11 = __builtin_amdgcn_mfma_f32_16x16x32_bf16(a1l, b1h, acc11, 0, 0, 0);
        }
        __syncthreads();
        apf += 32; aph += 32; if (TERMS == 3) apl += 32;
        bhp += 32; if (TERMS == 3) blp += 32;
    }

#pragma unroll
    for (int fg = 0; fg < 4; ++fg) {
        int f = fg >> 1, g = fg & 1;
        f4v a = (fg == 0) ? acc00 : (fg == 1) ? acc01 : (fg == 2) ? acc10 : acc11;
        int col = bn + wn * 32 + g * 16 + lr;
        int row0 = bm + wm * 32 + f * 16 + lc * 4;
#pragma unroll
        for (int j = 0; j < 4; ++j) {
            int rr = row0 + j;
            if (rr < M) {
                float vv = a[j];
                if (ATOM) {
                    atomicAdd(&C[(size_t)rr * N + col], vv);
                } else {
                    if (bias) vv += bias[col];
                    if (ACT == 1) vv = 0.5f * vv * (1.0f + erff(vv * 0.70710678118654752f));
                    if (RES) vv += Rsd[(size_t)rr * N + col];
                    if (OB == 1) ((u16*)C)[(size_t)rr * N + col] = f2bf(vv);
                    else         C[(size_t)rr * N + col] = vv;
                }
            }
        }
    }
}

// seq init: row 0 = class token, rows 1.. = embedding bias (atomic GEMM base)
__global__ void init_seq(float* __restrict__ seq, const float* __restrict__ bias,
                         const float* __restrict__ cls)
{
    int row = blockIdx.x;
    int t = threadIdx.x;
    seq[(size_t)row * 256 + t] = (row == 0) ? cls[t] : bias[t];
}

__global__ void pad_zero_u32(unsigned* __restrict__ p, int n)
{
    int i = blockIdx.x * 256 + threadIdx.x;
    if (i < n) p[i] = 0u;
}

__global__ void vecmat256(const float* __restrict__ v, const float* __restrict__ W,
                          float* __restrict__ out)
{
    int n = threadIdx.x;
    float acc = 0.f;
    for (int k = 0; k < 256; ++k) acc += v[k] * W[k * 256 + n];
    out[n] = acc;
}

// ---------------------------------------------------------------------------
// GAT pieces. No emax (scores |e| < ~0.3 -> exp safe); no denom atomic
// (aggregate sums weights in CSR order itself).
// ---------------------------------------------------------------------------
__global__ void gat_init(int* __restrict__ deg)
{
    int i = blockIdx.x * 256 + threadIdx.x;
    deg[i] = 0;
}

__global__ __launch_bounds__(256) void gat_scores(
    const u16* __restrict__ WH, const float* __restrict__ a_src,
    const float* __restrict__ a_dst, float* __restrict__ s_src,
    float* __restrict__ s_dst)
{
    int gid = blockIdx.x * 256 + threadIdx.x;
    int node = gid >> 6;
    int lane = gid & 63;
    uint2 rv = *(const uint2*)(WH + (size_t)node * D_MODEL + (lane << 2));
    float d0 = __uint_as_float(rv.x << 16);
    float d1 = __uint_as_float(rv.x & 0xffff0000u);
    float d2 = __uint_as_float(rv.y << 16);
    float d3 = __uint_as_float(rv.y & 0xffff0000u);
    float4 asv = *(const float4*)(a_src + (lane << 2));
    float4 adv = *(const float4*)(a_dst + (lane << 2));
    float as = d0 * asv.x + d1 * asv.y + d2 * asv.z + d3 * asv.w;
    float ad = d0 * adv.x + d1 * adv.y + d2 * adv.z + d3 * adv.w;
#pragma unroll
    for (int off = 32; off; off >>= 1) {
        as += __shfl_down(as, off);
        ad += __shfl_down(ad, off);
    }
    if (lane == 0) { s_src[node] = as; s_dst[node] = ad; }
}

// pass 1: degree count only (1 load + 1 atomic per edge)
__global__ void edge_deg(const int* __restrict__ ei, int* __restrict__ deg)
{
    int j = blockIdx.x * 256 + threadIdx.x;
    if (j >= EE_EDGES) return;
    int d = (j < E_EDGES) ? ei[E_EDGES + j] : j - E_EDGES;
    atomicAdd(&deg[d], 1);
}

__global__ void scan1(const int* __restrict__ in, int* __restrict__ out_excl,
                      int* __restrict__ bsum)
{
    __shared__ int s[256];
    int t = threadIdx.x;
    int i = blockIdx.x * 256 + t;
    int v = in[i];
    s[t] = v;
    __syncthreads();
    for (int off = 1; off < 256; off <<= 1) {
        int u = (t >= off) ? s[t - off] : 0;
        __syncthreads();
        s[t] += u;
        __syncthreads();
    }
    out_excl[i] = s[t] - v;
    if (t == 255) bsum[blockIdx.x] = s[255];
}

__global__ void scan2(int* __restrict__ bsum)
{
    __shared__ int s[256];
    int t = threadIdx.x;
    int v = bsum[t];
    s[t] = v;
    __syncthreads();
    for (int off = 1; off < 256; off <<= 1) {
        int u = (t >= off) ? s[t - off] : 0;
        __syncthreads();
        s[t] += u;
        __syncthreads();
    }
    bsum[t] = s[t] - v;
}

__global__ void scan3(int* __restrict__ offs, const int* __restrict__ bsum,
                      int* __restrict__ cur)
{
    int i = blockIdx.x * 256 + threadIdx.x;
    int v = offs[i] + bsum[blockIdx.x];
    offs[i] = v;
    cur[i] = v;
}

// pass 2: score + exp + CSR fill (cur atomic only)
__global__ void edge_fill(const int* __restrict__ ei, const float* __restrict__ s_src,
                          const float* __restrict__ s_dst, int* __restrict__ cur,
                          int* __restrict__ csr_src, float* __restrict__ csr_w)
{
    int j = blockIdx.x * 256 + threadIdx.x;
    if (j >= EE_EDGES) return;
    int s, d;
    if (j < E_EDGES) { s = ei[j]; d = ei[E_EDGES + j]; }
    else { s = d = j - E_EDGES; }
    float e = s_src[s] + s_dst[d];
    e = (e > 0.f) ? e : 0.2f * e;           // leaky_relu 0.2; |e| small -> exp safe
    int pos = atomicAdd(&cur[d], 1);
    csr_src[pos] = s;
    csr_w[pos] = __expf(e);
}

// bf16 WH gather, 4-way unrolled; weight-sum computed in-loop (no denom array)
__global__ __launch_bounds__(256) void gat_aggregate(
    const u16* __restrict__ WH, const int* __restrict__ csr_src,
    const float* __restrict__ csr_w, const int* __restrict__ offs,
    const int* __restrict__ deg, const float* __restrict__ b_gat,
    u16* __restrict__ hH)
{
    int gid = blockIdx.x * 256 + threadIdx.x;
    int node = gid >> 6;
    int lane = gid & 63;
    float a0 = 0.f, a1 = 0.f, a2 = 0.f, a3 = 0.f, wsum = 0.f;
    int s0 = offs[node], e0 = s0 + deg[node];
    int k = s0;
    for (; k + 4 <= e0; k += 4) {
        int i0 = csr_src[k], i1 = csr_src[k + 1];
        int i2 = csr_src[k + 2], i3 = csr_src[k + 3];
        float w0 = csr_w[k], w1 = csr_w[k + 1];
        float w2 = csr_w[k + 2], w3 = csr_w[k + 3];
        uint2 r0 = *(const uint2*)(WH + (size_t)i0 * D_MODEL + (lane << 2));
        uint2 r1 = *(const uint2*)(WH + (size_t)i1 * D_MODEL + (lane << 2));
        uint2 r2 = *(const uint2*)(WH + (size_t)i2 * D_MODEL + (lane << 2));
        uint2 r3 = *(const uint2*)(WH + (size_t)i3 * D_MODEL + (lane << 2));
        wsum += (w0 + w1) + (w2 + w3);
        a0 += w0 * __uint_as_float(r0.x << 16) + w1 * __uint_as_float(r1.x << 16)
            + w2 * __uint_as_float(r2.x << 16) + w3 * __uint_as_float(r3.x << 16);
        a1 += w0 * __uint_as_float(r0.x & 0xffff0000u) + w1 * __uint_as_float(r1.x & 0xffff0000u)
            + w2 * __uint_as_float(r2.x & 0xffff0000u) + w3 * __uint_as_float(r3.x & 0xffff0000u);
        a2 += w0 * __uint_as_float(r0.y << 16) + w1 * __uint_as_float(r1.y << 16)
            + w2 * __uint_as_float(r2.y << 16) + w3 * __uint_as_float(r3.y << 16);
        a3 += w0 * __uint_as_float(r0.y & 0xffff0000u) + w1 * __uint_as_float(r1.y & 0xffff0000u)
            + w2 * __uint_as_float(r2.y & 0xffff0000u) + w3 * __uint_as_float(r3.y & 0xffff0000u);
    }
    for (; k < e0; ++k) {
        int src = csr_src[k];
        float alpha = csr_w[k];
        uint2 rv = *(const uint2*)(WH + (size_t)src * D_MODEL + (lane << 2));
        wsum += alpha;
        a0 += alpha * __uint_as_float(rv.x << 16);
        a1 += alpha * __uint_as_float(rv.x & 0xffff0000u);
        a2 += alpha * __uint_as_float(rv.y << 16);
        a3 += alpha * __uint_as_float(rv.y & 0xffff0000u);
    }
    float inv = 1.0f / wsum;
    float4 bg = *(const float4*)(b_gat + (lane << 2));
    float v0 = a0 * inv + bg.x, v1 = a1 * inv + bg.y;
    float v2 = a2 * inv + bg.z, v3 = a3 * inv + bg.w;
    uint2 ho;
    ho.x = (unsigned)f2bf(v0) | ((unsigned)f2bf(v1) << 16);
    ho.y = (unsigned)f2bf(v2) | ((unsigned)f2bf(v3) << 16);
    *(uint2*)(hH + (size_t)node * D_MODEL + (lane << 2)) = ho;
}

// ---------------------------------------------------------------------------
// LayerNorm: writes Yh (bf16) and folds next GEMM's bias into seqio in place.
// ---------------------------------------------------------------------------
__global__ __launch_bounds__(256) void ln_kernel(
    float* __restrict__ seqio, const float* __restrict__ sc,
    const float* __restrict__ bi, u16* __restrict__ Yh,
    const float* __restrict__ badd)
{
    int row = blockIdx.x;
    int t = threadIdx.x;
    float x = seqio[(size_t)row * 256 + t];
    float sum = x, sq = x * x;
#pragma unroll
    for (int off = 32; off; off >>= 1) {
        sum += __shfl_down(sum, off);
        sq  += __shfl_down(sq, off);
    }
    __shared__ float rs[4], rq[4];
    if ((t & 63) == 0) { rs[t >> 6] = sum; rq[t >> 6] = sq; }
    __syncthreads();
    sum = rs[0] + rs[1] + rs[2] + rs[3];
    sq  = rq[0] + rq[1] + rq[2] + rq[3];
    float mean = sum * (1.f / 256.f);
    float var  = sq * (1.f / 256.f) - mean * mean;
    float r = rsqrtf(var + 1e-5f);
    float y = (x - mean) * r * sc[t] + bi[t];
    Yh[(size_t)row * 256 + t] = f2bf(y);
    seqio[(size_t)row * 256 + t] = x + badd[t];
}

// ---------------------------------------------------------------------------
// Split-KV MFMA flash attention. Grid (33, 8, NSPLIT).
// ---------------------------------------------------------------------------
__global__ __launch_bounds__(256) void mfma_attn_split(
    const u16* __restrict__ QKV, float* __restrict__ Opart,
    float* __restrict__ Mpart, float* __restrict__ Lpart)
{
    __shared__ __align__(16) u16 Ks[64 * 32];
    __shared__ __align__(16) u16 Vt[32 * 72];
    __shared__ __align__(16) u16 Ps[4 * 16 * 72];
    const int tid = threadIdx.x;
    const int w = tid >> 6, lane = tid & 63;
    const int g = lane >> 4, ql = lane & 15;
    const int h = blockIdx.y;
    const int sp = blockIdx.z;
    const int t0 = (33 * sp) / NSPLIT, t1 = (33 * (sp + 1)) / NSPLIT;
    const int qbase = blockIdx.x * 64 + w * 16;
    const float scale = 0.17677669529663687f;

    int qrow = qbase + ql; if (qrow > SEQ_LEN - 1) qrow = SEQ_LEN - 1;
    const s8v qfrag = *(const s8v*)(QKV + (size_t)qrow * 768 + h * 32 + g * 8);

    f4v o0 = {0.f, 0.f, 0.f, 0.f}, o1 = o0;
    float m[4], l[4];
#pragma unroll
    for (int r = 0; r < 4; ++r) { m[r] = -1e30f; l[r] = 0.f; }

    const int sr = tid >> 2, sc_ = tid & 3;
    const int kslot = sc_ ^ ((sr >> 1) & 3);
    u16* const psw = &Ps[w * 1152];

    for (int t = t0; t < t1; ++t) {
        __syncthreads();
        {
            int grow = t * 64 + sr;
            const u16* kp = QKV + (size_t)grow * 768 + 256 + h * 32 + sc_ * 8;
            s8v kvv = *(const s8v*)kp;
            s8v vvv = *(const s8v*)(kp + 256);
            *(s8v*)&Ks[sr * 32 + kslot * 8] = kvv;
#pragma unroll
            for (int e = 0; e < 8; ++e) Vt[(sc_ * 8 + e) * 72 + sr] = (u16)vvv[e];
        }
        __syncthreads();

        f4v s[4];
        const f4v zz = {0.f, 0.f, 0.f, 0.f};
#pragma unroll
        for (int c = 0; c < 4; ++c) {
            int kvloc = c * 16 + ql;
            s8v kf = *(s8v*)&Ks[kvloc * 32 + ((g ^ ((kvloc >> 1) & 3)) << 3)];
            s[c] = __builtin_amdgcn_mfma_f32_16x16x32_bf16(qfrag, kf, zz, 0, 0, 0);
            int kvg = t * 64 + kvloc;
            bool valid = (kvg < SEQ_LEN);
#pragma unroll
            for (int r = 0; r < 4; ++r)
                s[c][r] = valid ? s[c][r] * scale : -1e30f;
        }

        float mloc[4];
#pragma unroll
        for (int r = 0; r < 4; ++r) {
            float v = fmaxf(fmaxf(s[0][r], s[1][r]), fmaxf(s[2][r], s[3][r]));
            v = fmaxf(v, __shfl_xor(v, 1));
            v = fmaxf(v, __shfl_xor(v, 2));
            v = fmaxf(v, __shfl_xor(v, 4));
            v = fmaxf(v, __shfl_xor(v, 8));
            mloc[r] = v;
        }
        float fac[4];
#pragma unroll
        for (int r = 0; r < 4; ++r) {
            float mn = fmaxf(m[r], mloc[r]);
            fac[r] = __expf(m[r] - mn);
            m[r] = mn;
        }
#pragma unroll
        for (int c = 0; c < 4; ++c)
#pragma unroll
            for (int r = 0; r < 4; ++r)
                s[c][r] = __expf(s[c][r] - m[r]);
#pragma unroll
        for (int r = 0; r < 4; ++r) {
            float ls = s[0][r] + s[1][r] + s[2][r] + s[3][r];
            ls += __shfl_xor(ls, 1);
            ls += __shfl_xor(ls, 2);
            ls += __shfl_xor(ls, 4);
            ls += __shfl_xor(ls, 8);
            l[r] = l[r] * fac[r] + ls;
            o0[r] *= fac[r];
            o1[r] *= fac[r];
        }

#pragma unroll
        for (int c = 0; c < 4; ++c)
#pragma unroll
            for (int r = 0; r < 4; ++r)
                psw[(g * 4 + r) * 72 + c * 16 + ql] = f2bf(s[c][r]);

#pragma unroll
        for (int kch = 0; kch < 2; ++kch) {
            s8v pf = *(s8v*)&psw[ql * 72 + kch * 32 + g * 8];
            s8v v0 = *(s8v*)&Vt[ql * 72 + kch * 32 + g * 8];
            s8v v1 = *(s8v*)&Vt[(16 + ql) * 72 + kch * 32 + g * 8];
            o0 = __builtin_amdgcn_mfma_f32_16x16x32_bf16(pf, v0, o0, 0, 0, 0);
            o1 = __builtin_amdgcn_mfma_f32_16x16x32_bf16(pf, v1, o1, 0, 0, 0);
        }
    }

#pragma unroll
    for (int r = 0; r < 4; ++r) {
        int q = qbase + g * 4 + r;
        if (q < SEQ_LEN) {
            size_t base = ((size_t)sp * SEQ_PAD + q) * 256 + h * 32;
            Opart[base + ql] = o0[r];
            Opart[base + 16 + ql] = o1[r];
            if (ql == 0) {
                Mpart[((size_t)sp * SEQ_PAD + q) * NHEAD + h] = m[r];
                Lpart[((size_t)sp * SEQ_PAD + q) * NHEAD + h] = l[r];
            }
        }
    }
}

__global__ void cls_head(const float* __restrict__ seq, const float* __restrict__ W,
                         const float* __restrict__ b, float* __restrict__ out)
{
    __shared__ float s[256];
    int t = threadIdx.x;
    s[t] = seq[t];
    __syncthreads();
    if (t < NCLS) {
        float acc = b[t];
        for (int k = 0; k < 256; ++k) acc += s[k] * W[k * NCLS + t];
        out[t] = acc;
    }
}

// ---------------------------------------------------------------------------
extern "C" void kernel_launch(void* const* d_in, const int* in_sizes, int n_in,
                              void* d_out, int out_size, void* d_ws, size_t ws_size,
                              hipStream_t stream)
{
    (void)in_sizes; (void)n_in; (void)out_size; (void)ws_size;
    const float* x       = (const float*)d_in[0];
    const int*   ei      = (const int*)d_in[1];
    const float* W_in    = (const float*)d_in[2];
    const float* b_in    = (const float*)d_in[3];
    const float* W_gat   = (const float*)d_in[4];
    const float* a_src   = (const float*)d_in[5];
    const float* a_dst   = (const float*)d_in[6];
    const float* b_gat   = (const float*)d_in[7];
    const float* W_emb   = (const float*)d_in[8];
    const float* b_emb   = (const float*)d_in[9];
    const float* cls_tok = (const float*)d_in[10];
    const float* ln1_s   = (const float*)d_in[11];
    const float* ln1_b   = (const float*)d_in[12];
    const float* Wqkv    = (const float*)d_in[13];
    const float* bqkv    = (const float*)d_in[14];
    const float* Wproj   = (const float*)d_in[15];
    const float* bproj   = (const float*)d_in[16];
    const float* ln2_s   = (const float*)d_in[17];
    const float* ln2_b   = (const float*)d_in[18];
    const float* W1      = (const float*)d_in[19];
    const float* b1      = (const float*)d_in[20];
    const float* W2      = (const float*)d_in[21];
    const float* b2      = (const float*)d_in[22];
    const float* W_cls   = (const float*)d_in[23];
    const float* b_cls   = (const float*)d_in[24];
    float* out = (float*)d_out;

    // -------- workspace layout --------
    float* ws = (float*)d_ws;
    u16*   bufWHu = (u16*)ws;                  // N x 256 bf16 (GAT phase)
    float* seqb  = ws;                         // 524544 f (transformer phase)
    u16*   Yh    = (u16*)(ws + 524544);        // 524544 u16
    u16*   QKVb  = (u16*)(ws + 1049088);       // 2112*768 u16
    u16*   MLPHh = (u16*)(ws + 2384640);       // 2049*1024 u16
    u16*   wreg  = (u16*)(ws + 5500000);       // weights
    u16* embh  = wreg;
    u16* embl  = wreg + 2097152;
    u16* qkvh  = wreg + 4194304;
    u16* qkvl  = wreg + 5767168;
    u16* projh = wreg + 7340032;
    u16* projl = wreg + 7864320;
    u16* w1h   = wreg + 8388608;
    u16* w1l   = wreg + 10485760;
    u16* w2h   = wreg + 12582912;
    u16* w2l   = wreg + 14680064;
    // region B: hH (GAT output) — dead after embedding; attn partials alias it
    u16*   hH    = (u16*)(ws + 16777216);
    float* Opart = ws + 16777216;              // NSPLIT*2112*256 f
    float* Mpart = Opart + (size_t)NSPLIT * SEQ_PAD * 256;
    float* Lpart = Mpart + (size_t)NSPLIT * SEQ_PAD * NHEAD;
    float* sm    = ws + 2 * 16777216;
    float* s_src = sm;
    float* s_dst = sm + 65536;
    float* csr_w = sm + 2 * 65536;             // 589824
    float* Wc    = csr_w + 589824;             // 32768
    float* bc    = Wc + 32768;                 // 256
    int*   deg     = (int*)(bc + 256);
    int*   offs    = deg + 65536;
    int*   cur     = offs + 65536;
    int*   bsum    = cur + 65536;
    int*   csr_src = bsum + 256;
    u16*   wgTh = (u16*)(csr_src + 589824);
    u16*   wgTl = wgTh + 65536;
    u16*   wcTh = wgTh + 131072;
    u16*   wcTl = wcTh + 32768;

    // -------- GAT preprocessing --------
    gat_init<<<256, 256, 0, stream>>>(deg);
    prep_weight<<<dim3(4, 4, 1), 256, 0, stream>>>(W_gat, wgTh, wgTl, 256, 256,
                                                   0, 0, 1);
    hgemm<0,0,0,0,0,3,0><<<dim3(4, 2, 1), 256, 0, stream>>>(
        W_in, nullptr, wgTh, wgTl, nullptr, nullptr, Wc, nullptr, nullptr,
        128, 256, 256, 256);
    vecmat256<<<1, 256, 0, stream>>>(b_in, W_gat, bc);
    prep_weight<<<dim3(2, 4, 1), 256, 0, stream>>>(Wc, wcTh, wcTl, 128, 256,
                                                   0, 0, 0);
    hgemm<0,0,0,1,0,1,0><<<dim3(4, 1024, 1), 256, 0, stream>>>(
        x, nullptr, wcTh, nullptr, bc, nullptr, (float*)bufWHu, nullptr, nullptr,
        N_NODES, 256, 128, 128);
    gat_scores<<<16384, 256, 0, stream>>>(bufWHu, a_src, a_dst, s_src, s_dst);
    edge_deg<<<EE_EDGES / 256, 256, 0, stream>>>(ei, deg);
    scan1<<<256, 256, 0, stream>>>(deg, offs, bsum);
    scan2<<<1, 256, 0, stream>>>(bsum);
    scan3<<<256, 256, 0, stream>>>(offs, bsum, cur);
    edge_fill<<<EE_EDGES / 256, 256, 0, stream>>>(ei, s_src, s_dst, cur,
                                                  csr_src, csr_w);
    gat_aggregate<<<16384, 256, 0, stream>>>(bufWHu, csr_src, csr_w, offs, deg,
                                             b_gat, hH);

    // -------- weight prep (hi only for 1-term consumers) --------
    prep_weight<<<dim3(128, 4, 1), 256, 0, stream>>>(W_emb, embh, embl, 8192, 256,
                                                     0, 0, 0);
    prep_weight<<<dim3(4, 12, 8), 256, 0, stream>>>(Wqkv, qkvh, qkvl, 256, 768,
                                                    196608, 196608, 0);
    prep_weight<<<dim3(4, 4, 8), 256, 0, stream>>>(Wproj, projh, projl, 256, 256,
                                                   65536, 65536, 0);
    prep_weight<<<dim3(4, 16, 8), 256, 0, stream>>>(W1, w1h, w1l, 256, 1024,
                                                    262144, 262144, 0);
    prep_weight<<<dim3(16, 4, 8), 256, 0, stream>>>(W2, w2h, w2l, 1024, 256,
                                                    262144, 262144, 0);

    // -------- token embedding (split-K x8, atomic onto bias/cls-seeded seq) --
    init_seq<<<SEQ_LEN, 256, 0, stream>>>(seqb, b_emb, cls_tok);
    hgemm<0,0,1,0,1,1,0><<<dim3(4, 32, 8), 256, 0, stream>>>(
        (const void*)hH, nullptr, embh, nullptr, nullptr, nullptr, seqb + 256,
        nullptr, nullptr, 2048, 256, 8192, 1024);

    pad_zero_u32<<<95, 256, 0, stream>>>(
        (unsigned*)(QKVb + (size_t)SEQ_LEN * 768), (SEQ_PAD - SEQ_LEN) * 768 / 2);

    // -------- transformer layers --------
    for (int i = 0; i < 8; ++i) {
        // ln1: Y = LN(seq); seq += bproj (preadd for proj ATOM)
        ln_kernel<<<SEQ_LEN, 256, 0, stream>>>(seqb, ln1_s + i * 256,
                                               ln1_b + i * 256, Yh,
                                               bproj + i * 256);
        hgemm<0,0,0,1,1,1,0><<<dim3(12, 33, 1), 256, 0, stream>>>(
            (const void*)Yh, nullptr, qkvh + (size_t)i * 196608, nullptr,
            bqkv + i * 768, nullptr, (float*)QKVb, nullptr, nullptr,
            SEQ_LEN, 768, 256, 256);
        mfma_attn_split<<<dim3(33, NHEAD, NSPLIT), 256, 0, stream>>>(
            QKVb, Opart, Mpart, Lpart);
        // proj: split-K x4, atomic into seqb; combine fused into A-staging
        hgemm<0,0,1,0,0,1,1><<<dim3(4, 33, 4), 256, 0, stream>>>(
            (const void*)Opart, nullptr, projh + (size_t)i * 65536, nullptr,
            nullptr, nullptr, seqb, Mpart, Lpart, SEQ_LEN, 256, 256, 64);
        // ln2: Y = LN(seq); seq += b2 (preadd for mlp2 ATOM)
        ln_kernel<<<SEQ_LEN, 256, 0, stream>>>(seqb, ln2_s + i * 256,
                                               ln2_b + i * 256, Yh,
                                               b2 + i * 256);
        hgemm<1,0,0,1,1,1,0><<<dim3(16, 33, 1), 256, 0, stream>>>(
            (const void*)Yh, nullptr, w1h + (size_t)i * 262144, nullptr,
            b1 + i * 1024, nullptr, (float*)MLPHh, nullptr, nullptr,
            SEQ_LEN, 1024, 256, 256);
        hgemm<0,0,1,0,1,1,0><<<dim3(4, 33, 4), 256, 0, stream>>>(
            (const void*)MLPHh, nullptr, w2h + (size_t)i * 262144, nullptr,
            nullptr, nullptr, seqb, nullptr, nullptr, SEQ_LEN, 256, 1024, 256);
    }

    // -------- classifier head --------
    cls_head<<<1, 256, 0, stream>>>(seqb, W_cls, b_cls, out);
}